// Round 9
// baseline (41981.976 us; speedup 1.0000x reference)
//
#include <hip/hip_runtime.h>

// Problem constants
#define NB   128
#define LSEQ 2048
#define HID  512
#define EMB  256
#define KD   768
// Tiling: 256 blocks = 2 n-groups x 128 h-blocks (4 h each = 16 gate-rows)
// 512 threads = 16 nq (4 n's) x 4 hl x 8 kseg
#define NGR   2
#define HBL   128
#define NWG   256
#define NTHR  512
#define WSTR  772            // W row stride: 772%32=4 -> hl rows on disjoint bank quads
#define HN    (HID*NB)
#define RING  4

#define AT_RLX __ATOMIC_RELAXED
#define AT_REL __ATOMIC_RELEASE
#define SCOPE  __HIP_MEMORY_SCOPE_AGENT

typedef unsigned long long ull;

__device__ __forceinline__ void fma4(float4& a, const float4& v, float s) {
    a.x = fmaf(s, v.x, a.x); a.y = fmaf(s, v.y, a.y);
    a.z = fmaf(s, v.z, a.z); a.w = fmaf(s, v.w, a.w);
}
__device__ __forceinline__ void add4(float4& a, const float4& b) {
    a.x += b.x; a.y += b.y; a.z += b.z; a.w += b.w;
}
__device__ __forceinline__ float dot4(const float4& w, const float4& m) {
    return fmaf(w.x, m.x, fmaf(w.y, m.y, fmaf(w.z, m.z, w.w * m.w)));
}
__device__ __forceinline__ float sigf(float x) { return 1.0f / (1.0f + __expf(-x)); }
__device__ __forceinline__ float tanhfast(float x) { return fmaf(-2.0f, 1.0f / (1.0f + __expf(2.0f * x)), 1.0f); }
__device__ __forceinline__ float2 u2f(ull u) { union { ull u; float2 f; } c; c.u = u; return c.f; }
__device__ __forceinline__ ull f2u(float2 f) { union { ull u; float2 f; } c; c.f = f; return c.u; }

// Drain this wave's vmem (stores ack'd at LLC) then publish flag (tid0 lane).
__device__ __forceinline__ void publish_flag(int* fl, int val, int is_tid0) {
#if __has_builtin(__builtin_amdgcn_s_waitcnt)
    __builtin_amdgcn_s_waitcnt(0);     // vmcnt(0) lgkmcnt(0) expcnt(0)
    if (is_tid0) __hip_atomic_store(fl, val, AT_RLX, SCOPE);
#else
    if (is_tid0) __hip_atomic_store(fl, val, AT_REL, SCOPE);
#endif
}

__global__ void __launch_bounds__(NTHR, 2)
lstm_pers(const int* __restrict__ X, const float* __restrict__ E,
          const float* __restrict__ Ww, const float* __restrict__ Wb,
          float* __restrict__ out, float* __restrict__ ws)
{
    const int tid  = threadIdx.x;
    const int bid  = blockIdx.x;
    const int nb   = bid & (NGR - 1);          // n-group 0..1
    const int hb   = bid >> 1;                 // h-block 0..127
    const int nq   = tid & 15;                 // n-quad (4 n's)
    const int hl   = (tid >> 4) & 3;           // h within block
    const int kseg = tid >> 6;                 // 0..7, wave-uniform
    const int lid  = tid & 63;                 // (nq,hl)
    const int n0   = nb * 64 + nq * 4;         // global n (4 consecutive)
    const int hg   = hb * 4 + hl;              // global h
    const int h0   = hb * 4;

    __shared__ float  Wl[16 * WSTR];           // 49,408 B
    __shared__ float4 red[2][7][4][64];        // 57,344 B (double-buffered)

    float* Hring = ws;                          // RING * HN floats (1 MB)
    int*   flags = (int*)(ws + RING * HN);      // [nb][HBL] epoch flags

    // ---- stage W slice into LDS ----
    for (int i = tid; i < 16 * (KD / 4); i += NTHR) {
        int r = i / (KD / 4), c4 = i - r * (KD / 4);
        int g = r >> 2, h = r & 3;
        float4 v = *((const float4*)(Ww + (size_t)(g * HID + h0 + h) * KD) + c4);
        *(float4*)(Wl + r * WSTR + c4 * 4) = v;
    }
    float bF = 0, bI = 0, bO = 0, bT = 0;
    float cc0 = 0, cc1 = 0, cc2 = 0, cc3 = 0;   // cell state (gate wave, 4 n's)
    if (kseg == 0) {
        // zero H(0), ring slot 0 (bypass stores)
        __hip_atomic_store((ull*)&Hring[hg * NB + n0],     0ull, AT_RLX, SCOPE);
        __hip_atomic_store((ull*)&Hring[hg * NB + n0 + 2], 0ull, AT_RLX, SCOPE);
        bF = Wb[0 * HID + hg]; bI = Wb[1 * HID + hg];
        bO = Wb[2 * HID + hg]; bT = Wb[3 * HID + hg];
    }
    __syncthreads();                            // Wl staged before first E-part
    if (kseg == 0)
        publish_flag(&flags[nb * HBL + hb], 0, tid == 0);  // "H(0) ready"

    const float* Wr0 = Wl + (0 * 4 + hl) * WSTR;
    const float* Wr1 = Wl + (1 * 4 + hl) * WSTR;
    const float* Wr2 = Wl + (2 * 4 + hl) * WSTR;
    const float* Wr3 = Wl + (3 * 4 + hl) * WSTR;
    const int kb = kseg * 64;                   // H-part k base
    const int jb = kseg * 32;                   // E-part j base
    const int* fpoll = flags + nb * HBL + kseg * 16 + (tid & 15);  // one 64B line/wave

    for (int t = 0; t < LSEQ; ++t) {
        float4 a0 = {0,0,0,0}, a1 = {0,0,0,0}, a2 = {0,0,0,0}, a3 = {0,0,0,0};

        // ---- E-part (cached, no H dep; overlaps other blocks' producer tail) ----
        {
            int x0 = X[(n0 + 0) * LSEQ + t];
            int x1 = X[(n0 + 1) * LSEQ + t];
            int x2 = X[(n0 + 2) * LSEQ + t];
            int x3 = X[(n0 + 3) * LSEQ + t];
            const float* e0 = E + (size_t)x0 * EMB + jb;
            const float* e1 = E + (size_t)x1 * EMB + jb;
            const float* e2 = E + (size_t)x2 * EMB + jb;
            const float* e3 = E + (size_t)x3 * EMB + jb;
            #pragma unroll
            for (int j4 = 0; j4 < 8; ++j4) {
                int j = j4 * 4;
                float4 m0 = *(const float4*)(e0 + j);
                float4 m1 = *(const float4*)(e1 + j);
                float4 m2 = *(const float4*)(e2 + j);
                float4 m3 = *(const float4*)(e3 + j);
                float4 w0 = *(const float4*)(Wr0 + HID + jb + j);  // LDS 16-lane bcast
                float4 w1 = *(const float4*)(Wr1 + HID + jb + j);
                float4 w2 = *(const float4*)(Wr2 + HID + jb + j);
                float4 w3 = *(const float4*)(Wr3 + HID + jb + j);
                a0.x += dot4(w0, m0); a0.y += dot4(w0, m1); a0.z += dot4(w0, m2); a0.w += dot4(w0, m3);
                a1.x += dot4(w1, m0); a1.y += dot4(w1, m1); a1.z += dot4(w1, m2); a1.w += dot4(w1, m3);
                a2.x += dot4(w2, m0); a2.y += dot4(w2, m1); a2.z += dot4(w2, m2); a2.w += dot4(w2, m3);
                a3.x += dot4(w3, m0); a3.y += dot4(w3, m1); a3.z += dot4(w3, m2); a3.w += dot4(w3, m3);
            }
        }

        // ---- poll ONLY our 16 producers (one 64B flag line per iteration) ----
        while (!__all(__hip_atomic_load(fpoll, AT_RLX, SCOPE) >= t))
            __builtin_amdgcn_s_sleep(1);

        const float* Hc = Hring + (t & (RING - 1)) * HN;
        float*       Hw = Hring + ((t + 1) & (RING - 1)) * HN;

        // ---- H-part: 64 k's, bypass 8B loads (LLC-fresh), chunks of 8 k ----
        #pragma unroll
        for (int c = 0; c < 8; ++c) {
            int k = kb + c * 8;
            ull rA[8], rB[8];
            #pragma unroll
            for (int j = 0; j < 8; ++j) {       // 16 loads issue back-to-back
                rA[j] = __hip_atomic_load((const ull*)&Hc[(k + j) * NB + n0],     AT_RLX, SCOPE);
                rB[j] = __hip_atomic_load((const ull*)&Hc[(k + j) * NB + n0 + 2], AT_RLX, SCOPE);
            }
            #pragma unroll
            for (int q = 0; q < 2; ++q) {       // k-groups of 4
                int kk = k + q * 4;
                float4 w0 = *(const float4*)(Wr0 + kk);
                float4 w1 = *(const float4*)(Wr1 + kk);
                float4 w2 = *(const float4*)(Wr2 + kk);
                float4 w3 = *(const float4*)(Wr3 + kk);
                #pragma unroll
                for (int i = 0; i < 4; ++i) {
                    float2 hA = u2f(rA[q * 4 + i]), hB = u2f(rB[q * 4 + i]);
                    float4 hv = make_float4(hA.x, hA.y, hB.x, hB.y);
                    float wi0 = (i == 0) ? w0.x : (i == 1) ? w0.y : (i == 2) ? w0.z : w0.w;
                    float wi1 = (i == 0) ? w1.x : (i == 1) ? w1.y : (i == 2) ? w1.z : w1.w;
                    float wi2 = (i == 0) ? w2.x : (i == 1) ? w2.y : (i == 2) ? w2.z : w2.w;
                    float wi3 = (i == 0) ? w3.x : (i == 1) ? w3.y : (i == 2) ? w3.z : w3.w;
                    fma4(a0, hv, wi0); fma4(a1, hv, wi1);
                    fma4(a2, hv, wi2); fma4(a3, hv, wi3);
                }
            }
        }

        // ---- reduction: ksegs 1..7 deposit partials (double-buffered) ----
        float4 (*rb)[4][64] = red[t & 1];
        if (kseg != 0) {
            rb[kseg - 1][0][lid] = a0; rb[kseg - 1][1][lid] = a1;
            rb[kseg - 1][2][lid] = a2; rb[kseg - 1][3][lid] = a3;
        }
        __syncthreads();   // the ONLY per-step block barrier

        if (kseg == 0) {
            #pragma unroll
            for (int s = 0; s < 7; ++s) {
                add4(a0, rb[s][0][lid]); add4(a1, rb[s][1][lid]);
                add4(a2, rb[s][2][lid]); add4(a3, rb[s][3][lid]);
            }
            // gates + state + H publish (h fixed, 4 n's)
            float F, I, O, T, v0, v1, v2, v3;
            F = sigf(a0.x + bF); I = sigf(a1.x + bI); O = sigf(a2.x + bO); T = tanhfast(a3.x + bT);
            cc0 = fmaf(F, cc0, I * T); v0 = O * tanhfast(cc0);
            F = sigf(a0.y + bF); I = sigf(a1.y + bI); O = sigf(a2.y + bO); T = tanhfast(a3.y + bT);
            cc1 = fmaf(F, cc1, I * T); v1 = O * tanhfast(cc1);
            F = sigf(a0.z + bF); I = sigf(a1.z + bI); O = sigf(a2.z + bO); T = tanhfast(a3.z + bT);
            cc2 = fmaf(F, cc2, I * T); v2 = O * tanhfast(cc2);
            F = sigf(a0.w + bF); I = sigf(a1.w + bI); O = sigf(a2.w + bO); T = tanhfast(a3.w + bT);
            cc3 = fmaf(F, cc3, I * T); v3 = O * tanhfast(cc3);
            __hip_atomic_store((ull*)&Hw[hg * NB + n0],     f2u(make_float2(v0, v1)), AT_RLX, SCOPE);
            __hip_atomic_store((ull*)&Hw[hg * NB + n0 + 2], f2u(make_float2(v2, v3)), AT_RLX, SCOPE);
            if (t == LSEQ - 1) {
                __hip_atomic_store(&out[(size_t)(n0 + 0) * HID + hg], v0, AT_RLX, SCOPE);
                __hip_atomic_store(&out[(size_t)(n0 + 1) * HID + hg], v1, AT_RLX, SCOPE);
                __hip_atomic_store(&out[(size_t)(n0 + 2) * HID + hg], v2, AT_RLX, SCOPE);
                __hip_atomic_store(&out[(size_t)(n0 + 3) * HID + hg], v3, AT_RLX, SCOPE);
            }
            // gate-wave-only drain + flag: no block barrier on the critical path.
            publish_flag(&flags[nb * HBL + hb], t + 1, tid == 0);
        }
        // Non-gate waves are already running step t+1's E-part here. red-buffer
        // reuse is safe: ST(t+2) into this buffer happens only after the next
        // __syncthreads, which the gate wave reaches only after its LD above.
    }
}

extern "C" void kernel_launch(void* const* d_in, const int* in_sizes, int n_in,
                              void* d_out, int out_size, void* d_ws, size_t ws_size,
                              hipStream_t stream) {
    const int*   X   = (const int*)d_in[0];
    const float* E   = (const float*)d_in[1];
    const float* Ww  = (const float*)d_in[2];
    const float* Wb  = (const float*)d_in[3];
    float*       out = (float*)d_out;
    float*       ws  = (float*)d_ws;
    void* args[] = { (void*)&X, (void*)&E, (void*)&Ww, (void*)&Wb, (void*)&out, (void*)&ws };
    hipError_t e = hipLaunchCooperativeKernel((const void*)lstm_pers, dim3(NWG), dim3(NTHR),
                                              args, 0, stream);
    if (e != hipSuccess) {
        // 256 blocks, ~107KB LDS -> 1 block/CU, co-resident on idle 256-CU chip.
        hipLaunchKernelGGL(lstm_pers, dim3(NWG), dim3(NTHR), 0, stream,
                           X, E, Ww, Wb, out, ws);
    }
}

// Round 10
// 18519.926 us; speedup vs baseline: 2.2669x; 2.2669x over previous
//
#include <hip/hip_runtime.h>

// Problem constants
#define NB   128
#define LSEQ 2048
#define HID  512
#define EMB  256
#define KD   768
// Structure: batch rows are INDEPENDENT. 8 n-groups x 16 n; each group split
// over 32 h-blocks x 16 h. 256 blocks, 512 threads = 8 waves, K split 96/wave.
#define NGRP  8
#define NPG   16
#define HBLK  32
#define HPB   16
#define NWG   256
#define NTHR  512
#define RING  4
#define KSL   96

#define AT_RLX __ATOMIC_RELAXED
#define AT_REL __ATOMIC_RELEASE
#define SCOPE  __HIP_MEMORY_SCOPE_AGENT

typedef unsigned long long ull;
typedef _Float16 f16;
typedef f16   f16x8 __attribute__((ext_vector_type(8)));
typedef float f32x4 __attribute__((ext_vector_type(4)));

__device__ __forceinline__ float sigf(float x) { return 1.0f / (1.0f + __expf(-x)); }
__device__ __forceinline__ float tanhfast(float x) { return fmaf(-2.0f, 1.0f / (1.0f + __expf(2.0f * x)), 1.0f); }

// Drain this wave's vmem (stores ack'd at LLC) then lane0 publishes the flag.
__device__ __forceinline__ void publish_flag(int* fl, int val, int is_l0) {
#if __has_builtin(__builtin_amdgcn_s_waitcnt)
    __builtin_amdgcn_s_waitcnt(0);
    if (is_l0) __hip_atomic_store(fl, val, AT_RLX, SCOPE);
#else
    if (is_l0) __hip_atomic_store(fl, val, AT_REL, SCOPE);
#endif
}

__global__ void __launch_bounds__(NTHR, 2)
lstm_pers(const int* __restrict__ X, const float* __restrict__ E,
          const float* __restrict__ Ww, const float* __restrict__ Wb,
          float* __restrict__ out, float* __restrict__ ws)
{
    const int tid  = threadIdx.x;
    const int bid  = blockIdx.x;
    const int ng   = bid & (NGRP - 1);     // n-group (bid&7 -> XCD-local heuristic)
    const int hb   = bid >> 3;             // h-block 0..31
    const int w    = tid >> 6;             // wave 0..7
    const int lane = tid & 63;
    const int quad = lane >> 4;
    const int m16  = lane & 15;
    const int ks   = w * KSL;              // this wave's K base (96 wide)

    __shared__ float red[2][8][4][16][16];  // 64 KB: [buf][wave][gate][n][h]

    f16* Hbuf  = (f16*)ws;                              // [grp][slot][n][HID] fp16
    int* flags = (int*)((char*)ws + (size_t)NGRP * RING * NPG * HID * 2); // [grp][32]

    // ---- init: W fragments -> VGPRs (fp16), persistent for whole kernel ----
    // A-frag layout (16x16x32): lane holds A[m=lane&15][k=quad*8+j], j=0..7.
    // M-tile = gate g (16 rows = the 16 h of this block), K-tiles ti=0..2.
    f16x8 wf[4][3];
    #pragma unroll
    for (int g = 0; g < 4; ++g) {
        #pragma unroll
        for (int ti = 0; ti < 3; ++ti) {
            const float* wp = Ww + (size_t)(g * HID + hb * HPB + m16) * KD
                                 + (ks + ti * 32 + quad * 8);
            f16x8 v;
            #pragma unroll
            for (int j = 0; j < 8; ++j) v[j] = (f16)wp[j];
            wf[g][ti] = v;
        }
    }
    // bias + cell state live in wave 7 (the epilogue wave; polls nothing)
    f32x4 bias[4], cst = {0, 0, 0, 0};
    if (w == 7) {
        #pragma unroll
        for (int g = 0; g < 4; ++g)
            bias[g] = *(const f32x4*)(Wb + g * HID + hb * HPB + quad * 4);
        // zero H(0) slot 0: lane covers (n=lane>>2, 4 h's = (lane&3)*4)
        ull* z = (ull*)(Hbuf + ((size_t)(ng * RING + 0) * NPG + (lane >> 2)) * HID
                        + hb * HPB + (lane & 3) * 4);
        __hip_atomic_store(z, 0ull, AT_RLX, SCOPE);
    }
    __syncthreads();
    if (w == 7) publish_flag(&flags[ng * 32 + hb], 0, lane == 0);

    // poll set: h-blocks covered by this wave's H-k range [ks, ks+96) n 512
    int nf = 0, fb = 0;
    if (w < 5)      { nf = 6; fb = 6 * w; }
    else if (w == 5){ nf = 2; fb = 30; }
    const int* fp = flags + ng * 32 + fb + ((lane < nf) ? lane : 0);

    for (int t = 0; t < LSEQ; ++t) {
        f16x8 bf[3];
        // ---- E tiles first (cached reads, no sync dependency) ----
        if (ks + 2 * 32 >= HID) {                    // wave has >=1 E tile
            int xi = X[(ng * NPG + m16) * LSEQ + t];
            const float* eb = E + (size_t)xi * EMB;
            #pragma unroll
            for (int ti = 0; ti < 3; ++ti) {
                int k0 = ks + ti * 32;
                if (k0 >= HID) {
                    const float* ep = eb + (k0 - HID) + quad * 8;
                    f32x4 e0 = *(const f32x4*)(ep);
                    f32x4 e1 = *(const f32x4*)(ep + 4);
                    f16x8 v;
                    #pragma unroll
                    for (int j = 0; j < 4; ++j) { v[j] = (f16)e0[j]; v[4 + j] = (f16)e1[j]; }
                    bf[ti] = v;
                }
            }
        }
        // ---- poll only the <=6 producers this wave's K-slice needs ----
        if (nf > 0) {
            while (!__all((lane < nf) ? (__hip_atomic_load(fp, AT_RLX, SCOPE) >= t) : true))
                __builtin_amdgcn_s_sleep(1);
        }
        // ---- H tiles: bypass 2x8B loads, B[n=lane&15][k=quad*8+j] fp16 ----
        const f16* Hc = Hbuf + (size_t)(ng * RING + (t & 3)) * NPG * HID;
        #pragma unroll
        for (int ti = 0; ti < 3; ++ti) {
            int k0 = ks + ti * 32;
            if (k0 < HID) {
                const ull* hp = (const ull*)(Hc + (size_t)m16 * HID + k0 + quad * 8);
                union { ull u[2]; f16x8 v; } cv;
                cv.u[0] = __hip_atomic_load(hp,     AT_RLX, SCOPE);
                cv.u[1] = __hip_atomic_load(hp + 1, AT_RLX, SCOPE);
                bf[ti] = cv.v;
            }
        }
        // ---- MFMA: 4 gates x 3 K-tiles ----
        f32x4 acc[4] = {{0,0,0,0},{0,0,0,0},{0,0,0,0},{0,0,0,0}};
        #pragma unroll
        for (int ti = 0; ti < 3; ++ti)
            #pragma unroll
            for (int g = 0; g < 4; ++g)
                acc[g] = __builtin_amdgcn_mfma_f32_16x16x32_f16(wf[g][ti], bf[ti], acc[g], 0, 0, 0);

        // ---- deposit partials: D[row=quad*4+r][col=n=m16] -> red[w][g][n][4q..] ----
        #pragma unroll
        for (int g = 0; g < 4; ++g)
            *(f32x4*)&red[t & 1][w][g][m16][quad * 4] = acc[g];
        __syncthreads();                       // the only per-step block barrier

        if (w == 7) {
            // reduce 8 waves, add bias: lane owns n=m16, h = quad*4 .. +3
            f32x4 G[4];
            #pragma unroll
            for (int g = 0; g < 4; ++g) {
                f32x4 s = bias[g];
                #pragma unroll
                for (int wv = 0; wv < 8; ++wv) {
                    f32x4 r = *(const f32x4*)&red[t & 1][wv][g][m16][quad * 4];
                    s.x += r.x; s.y += r.y; s.z += r.z; s.w += r.w;
                }
                G[g] = s;
            }
            // gates + cell update; 4 h's per lane, contiguous -> one 8B store
            union { f16 h[4]; ull u; } pk;
            f32x4 ov;
            #pragma unroll
            for (int s = 0; s < 4; ++s) {
                float F = sigf(G[0][s]);
                float I = sigf(G[1][s]);
                float O = sigf(G[2][s]);
                float T = tanhfast(G[3][s]);
                cst[s] = fmaf(F, cst[s], I * T);
                float hn = O * tanhfast(cst[s]);
                pk.h[s] = (f16)hn;
                ov[s] = hn;
            }
            f16* Hw = Hbuf + (size_t)(ng * RING + ((t + 1) & 3)) * NPG * HID;
            __hip_atomic_store((ull*)(Hw + (size_t)m16 * HID + hb * HPB + quad * 4),
                               pk.u, AT_RLX, SCOPE);
            if (t == LSEQ - 1)
                *(f32x4*)(out + (size_t)(ng * NPG + m16) * HID + hb * HPB + quad * 4) = ov;
            publish_flag(&flags[ng * 32 + hb], t + 1, lane == 0);
        }
        // Other waves run ahead into t+1 (E-part + their own polls). red is
        // double-buffered; their next write targets red[(t+1)&1], and writes to
        // red[t&1] can only recur after the t+1 barrier, which wave 7 reaches
        // only after finishing this epilogue. Slot safety: skew across blocks
        // is 0 at poll (flags>=t => all peers completed t-1), so reads hit
        // slot t&3 while writes hit (t+1)&3 - always disjoint.
    }
}

extern "C" void kernel_launch(void* const* d_in, const int* in_sizes, int n_in,
                              void* d_out, int out_size, void* d_ws, size_t ws_size,
                              hipStream_t stream) {
    const int*   X   = (const int*)d_in[0];
    const float* E   = (const float*)d_in[1];
    const float* Ww  = (const float*)d_in[2];
    const float* Wb  = (const float*)d_in[3];
    float*       out = (float*)d_out;
    float*       ws  = (float*)d_ws;
    void* args[] = { (void*)&X, (void*)&E, (void*)&Ww, (void*)&Wb, (void*)&out, (void*)&ws };
    hipError_t e = hipLaunchCooperativeKernel((const void*)lstm_pers, dim3(NWG), dim3(NTHR),
                                              args, 0, stream);
    if (e != hipSuccess) {
        // 256 blocks, 64KB LDS, ~130 VGPR -> 1 block/CU co-resident on 256 CUs.
        hipLaunchKernelGGL(lstm_pers, dim3(NWG), dim3(NTHR), 0, stream,
                           X, E, Ww, Wb, out, ws);
    }
}